// Round 13
// baseline (103.412 us; speedup 1.0000x reference)
//
#include <hip/hip_runtime.h>
#include <hip/hip_bf16.h>

#define B_SENT 128
#define L_TOK  256
#define D_DIM  1024
#define TM     64              // tokens per block = 4 waves x 16 rows
#define BK     32              // K per step == MFMA K
#define NKB    (D_DIM / BK)    // 32 K-steps

typedef __attribute__((ext_vector_type(8))) short bf16x8;
typedef __attribute__((ext_vector_type(4))) float f32x4;

__device__ __forceinline__ unsigned short f2bf(float f) {
    return __builtin_bit_cast(unsigned short, __float2bfloat16(f));
}
__device__ __forceinline__ float softplus_f(float x) {
    float ax = fabsf(x);
    return fmaxf(x, 0.0f) + __logf(1.0f + __expf(-ax));
}
__device__ __forceinline__ bf16x8 cvt8f(const f32x4& lo, const f32x4& hi) {
    bf16x8 u;
    u[0] = (short)f2bf(lo[0]); u[1] = (short)f2bf(lo[1]);
    u[2] = (short)f2bf(lo[2]); u[3] = (short)f2bf(lo[3]);
    u[4] = (short)f2bf(hi[0]); u[5] = (short)f2bf(hi[1]);
    u[6] = (short)f2bf(hi[2]); u[7] = (short)f2bf(hi[3]);
    return u;
}

// async global->LDS, 16 B per lane. LDS base wave-uniform; global src per-lane.
__device__ __forceinline__ void gl_lds16(const void* g, void* l) {
    __builtin_amdgcn_global_load_lds(
        (const __attribute__((address_space(1))) unsigned int*)g,
        (__attribute__((address_space(3))) unsigned int*)l, 16, 0, 0);
}

// ---------------------------------------------------------------------------
// Pre-pack glob (f32) -> bf16 MFMA B-fragments, BK=32 chunks (512 KB total):
// packed[((side*32+kb)*512 + n*64 + lane)*8 + e]
//   = glob[side][n*16+(lane&15)][kb*32+(lane>>4)*8+e]
// ---------------------------------------------------------------------------
__global__ __launch_bounds__(256) void pack_g_kernel(
    const float* __restrict__ g0, const float* __restrict__ g1,
    short* __restrict__ packed)
{
    const int idx  = blockIdx.x * 256 + threadIdx.x;   // 0..32767
    const int lane = idx & 63;
    const int n    = (idx >> 6) & 7;
    const int kb   = (idx >> 9) & 31;
    const int side = idx >> 14;
    const int row  = n * 16 + (lane & 15);
    const int col  = kb * 32 + (lane >> 4) * 8;
    const float* g = side ? g1 : g0;
    const f32x4 v0 = *reinterpret_cast<const f32x4*>(&g[(size_t)row * D_DIM + col]);
    const f32x4 v1 = *reinterpret_cast<const f32x4*>(&g[(size_t)row * D_DIM + col + 4]);
    *reinterpret_cast<bf16x8*>(&packed[(size_t)idx * 8]) = cvt8f(v0, v1);
}

// ---------------------------------------------------------------------------
// Main: BARRIER-FREE wave-private pipeline. Block = 4 waves; wave owns
// 16 tokens x 128 sentences and stages ONLY its own data into private LDS
// (2 A + 8 B gl_lds per K-step). Own counted vmcnt, zero s_barrier in loop:
// waves drift independently, hiding each other's HBM latency.
// Order per step: wait(own stage kb) -> compute(kb) -> stage(kb+2) into the
// buffer just consumed (sched_barrier fences keep ds_reads above the
// overwriting gl_lds; data-return >= issue makes the WAR safe).
// ---------------------------------------------------------------------------
__global__ __launch_bounds__(256, 2) void mi_main_kernel(
    const float* __restrict__ tok0, const float* __restrict__ tok1,
    const int* __restrict__ len0, const int* __restrict__ len1,
    const short* __restrict__ packed, float* __restrict__ acc_ws)
{
    const int side = blockIdx.y;
    const float* tok = side ? tok1 : tok0;
    const int*   len = side ? len1 : len0;

    const int tile   = blockIdx.x;       // 0..511
    const int b_sent = tile >> 2;        // 4 tiles per sentence
    const int toff   = (tile & 3) * TM;
    const int count  = max(1, len[b_sent]) - toff;
    if (count <= 0) return;              // uniform whole-block exit
    const int tb     = b_sent * L_TOK + toff;

    const int tid  = threadIdx.x;
    const int wave = tid >> 6;           // 0..3
    const int lane = tid & 63;
    const int lrow = lane & 15;
    const int kgrp = lane >> 4;

    __shared__ float As[4][2][512];      // per wave, per buf: 2 KB (16r x 32c f32)
    __shared__ short Bs[4][2][4096];     // per wave, per buf: 8 KB (8 frags)
    __shared__ float sred[8];

    // A source: wave's own 16 token rows, clamped (dups hit cache; masked
    // rows are skipped by the epilogue).
    const int srow = min(wave * 16 + lrow, count - 1);
    const float* asrc = tok + (size_t)(tb + srow) * D_DIM + kgrp * 8;
    const short* bchunk = packed + (size_t)side * NKB * 4096;

    f32x4 acc[8];
#pragma unroll
    for (int n = 0; n < 8; ++n) acc[n] = (f32x4){0.f, 0.f, 0.f, 0.f};

    auto stage = [&](int buf, int kb) {          // exactly 10 gl_lds, fixed order
        const float* a = asrc + kb * BK;
        gl_lds16(a,     &As[wave][buf][0]);
        gl_lds16(a + 4, &As[wave][buf][256]);
        const short* bc = bchunk + (size_t)kb * 4096;
#pragma unroll
        for (int n = 0; n < 8; ++n)
            gl_lds16(bc + (n * 64 + lane) * 8, &Bs[wave][buf][n * 512]);
    };

    auto compute = [&](int buf) {
        const f32x4 alo = *reinterpret_cast<const f32x4*>(&As[wave][buf][lane * 4]);
        const f32x4 ahi = *reinterpret_cast<const f32x4*>(&As[wave][buf][256 + lane * 4]);
        const bf16x8 af = cvt8f(alo, ahi);
#pragma unroll
        for (int n = 0; n < 8; ++n) {
            bf16x8 b = *reinterpret_cast<const bf16x8*>(&Bs[wave][buf][(n * 64 + lane) * 8]);
            acc[n] = __builtin_amdgcn_mfma_f32_16x16x32_bf16(af, b, acc[n], 0, 0, 0);
        }
    };

#define WAITVM(N) do {                                                       \
        asm volatile("s_waitcnt vmcnt(" #N ")" ::: "memory");                \
        __builtin_amdgcn_sched_barrier(0);                                   \
    } while (0)
#define FENCE() __builtin_amdgcn_sched_barrier(0)

    // prologue: 2 stages in flight (20 VMEM ops/wave)
    stage(0, 0);
    stage(1, 1);
#pragma unroll 2
    for (int kb = 0; kb < NKB - 2; ++kb) {   // kb = 0..29
        WAITVM(10);                          // own stage kb landed
        compute(kb & 1);
        FENCE();                             // ds_reads stay above the overwrite
        stage(kb & 1, kb + 2);               // refill the buffer just consumed
    }
    WAITVM(10); compute(0);                  // kb = 30
    WAITVM(0);  compute(1);                  // kb = 31
#undef WAITVM
#undef FENCE

    // ---- epilogue: masked softplus reduction ----
    // C/D layout: col = lane&15 (sentence), row = kgrp*4 + j (token in frag)
    float ep = 0.f, en = 0.f;
#pragma unroll
    for (int n = 0; n < 8; ++n) {
        const int g = n * 16 + lrow;               // global sentence id
#pragma unroll
        for (int j = 0; j < 4; ++j) {
            const int rl = wave * 16 + kgrp * 4 + j;   // local token row
            if (rl < count) {
                float res = acc[n][j];
                float sp  = softplus_f(res);
                if (g == b_sent) ep += res - sp;   // -softplus(-res)
                else             en += sp;         // softplus(-res)+res
            }
        }
    }

#pragma unroll
    for (int off = 32; off; off >>= 1) {
        ep += __shfl_down(ep, off);
        en += __shfl_down(en, off);
    }
    if (lane == 0) { sred[wave * 2] = ep; sred[wave * 2 + 1] = en; }
    __syncthreads();
    if (tid == 0) {
        float tep = sred[0] + sred[2] + sred[4] + sred[6];
        float ten = sred[1] + sred[3] + sred[5] + sred[7];
        atomicAdd(&acc_ws[side * 2 + 0], tep);
        atomicAdd(&acc_ws[side * 2 + 1], ten);
    }
}

__global__ void mi_finalize_kernel(const int* __restrict__ len0,
                                   const int* __restrict__ len1,
                                   const float* __restrict__ acc_ws,
                                   float* __restrict__ out)
{
    const int lane = threadIdx.x;   // 1 wave
    int s0 = 0, s1 = 0;
    for (int i = lane; i < B_SENT; i += 64) {
        s0 += max(1, len0[i]);
        s1 += max(1, len1[i]);
    }
#pragma unroll
    for (int off = 32; off; off >>= 1) {
        s0 += __shfl_down(s0, off);
        s1 += __shfl_down(s1, off);
    }
    if (lane == 0) {
        const float num_nodes = (float)(s0 + s1);
        const float ep = acc_ws[0] + acc_ws[2];
        const float en = acc_ws[1] + acc_ws[3];
        out[0] = en / (num_nodes * (float)(B_SENT - 1)) - ep / num_nodes;
        out[1] = ((float)s0 + (float)s1) / (2.0f * (float)B_SENT);
    }
}

extern "C" void kernel_launch(void* const* d_in, const int* in_sizes, int n_in,
                              void* d_out, int out_size, void* d_ws, size_t ws_size,
                              hipStream_t stream) {
    const float* tok0  = (const float*)d_in[0];
    const float* tok1  = (const float*)d_in[1];
    const float* glob0 = (const float*)d_in[2];
    const float* glob1 = (const float*)d_in[3];
    const int*   len0  = (const int*)d_in[4];
    const int*   len1  = (const int*)d_in[5];
    float* out = (float*)d_out;

    float* acc    = (float*)d_ws;                       // 4 floats @ offset 0
    short* packed = (short*)((char*)d_ws + 256);        // 512 KB bf16 fragments

    hipMemsetAsync(d_ws, 0, 256, stream);
    pack_g_kernel<<<128, 256, 0, stream>>>(glob0, glob1, packed);

    dim3 grid(32768 / TM, 2);   // 512 token-tiles x 2 sides
    mi_main_kernel<<<grid, 256, 0, stream>>>(tok0, tok1, len0, len1, packed, acc);
    mi_finalize_kernel<<<1, 64, 0, stream>>>(len0, len1, acc, out);
}

// Round 14
// 65.198 us; speedup vs baseline: 1.5861x; 1.5861x over previous
//
#include <hip/hip_runtime.h>
#include <hip/hip_bf16.h>

#define B_SENT 128
#define L_TOK  256
#define D_DIM  1024
#define TM     64              // tokens per block = 4 waves x 16 rows
#define BK     32              // K per step == MFMA K
#define NKB    (D_DIM / BK)    // 32 K-steps

typedef __attribute__((ext_vector_type(8))) short bf16x8;
typedef __attribute__((ext_vector_type(4))) float f32x4;

__device__ __forceinline__ unsigned short f2bf(float f) {
    return __builtin_bit_cast(unsigned short, __float2bfloat16(f));
}
__device__ __forceinline__ float softplus_f(float x) {
    float ax = fabsf(x);
    return fmaxf(x, 0.0f) + __logf(1.0f + __expf(-ax));
}
__device__ __forceinline__ bf16x8 cvt8f(const f32x4& lo, const f32x4& hi) {
    bf16x8 u;
    u[0] = (short)f2bf(lo[0]); u[1] = (short)f2bf(lo[1]);
    u[2] = (short)f2bf(lo[2]); u[3] = (short)f2bf(lo[3]);
    u[4] = (short)f2bf(hi[0]); u[5] = (short)f2bf(hi[1]);
    u[6] = (short)f2bf(hi[2]); u[7] = (short)f2bf(hi[3]);
    return u;
}

// async global->LDS, 16 B per lane. LDS base wave-uniform; global src per-lane.
__device__ __forceinline__ void gl_lds16(const void* g, void* l) {
    __builtin_amdgcn_global_load_lds(
        (const __attribute__((address_space(1))) unsigned int*)g,
        (__attribute__((address_space(3))) unsigned int*)l, 16, 0, 0);
}

// ---------------------------------------------------------------------------
// Pre-pack glob (f32) -> bf16 MFMA B-fragments, BK=32 chunks (512 KB total):
// packed[((side*32+kb)*512 + n*64 + lane)*8 + e]
//   = glob[side][n*16+(lane&15)][kb*32+(lane>>4)*8+e]
// ---------------------------------------------------------------------------
__global__ __launch_bounds__(256) void pack_g_kernel(
    const float* __restrict__ g0, const float* __restrict__ g1,
    short* __restrict__ packed)
{
    const int idx  = blockIdx.x * 256 + threadIdx.x;   // 0..32767
    const int lane = idx & 63;
    const int n    = (idx >> 6) & 7;
    const int kb   = (idx >> 9) & 31;
    const int side = idx >> 14;
    const int row  = n * 16 + (lane & 15);
    const int col  = kb * 32 + (lane >> 4) * 8;
    const float* g = side ? g1 : g0;
    const f32x4 v0 = *reinterpret_cast<const f32x4*>(&g[(size_t)row * D_DIM + col]);
    const f32x4 v1 = *reinterpret_cast<const f32x4*>(&g[(size_t)row * D_DIM + col + 4]);
    *reinterpret_cast<bf16x8*>(&packed[(size_t)idx * 8]) = cvt8f(v0, v1);
}

// ---------------------------------------------------------------------------
// Main R14: A fragments = per-lane VOLATILE float4 pairs straight to regs
// (lane l's MFMA A operand IS its own 8 floats: row l&15, cols (l>>4)*8..+8),
// 2-deep ping-pong; volatile defeats IR-level load sinking, compiler inserts
// the correct vmcnt before the cvt use. B = gl_lds into 3 shared 8 KB bufs,
// counted vmcnt(6)+s_barrier (2-step slack; over-drain-safe if loads split).
// Block = 4 waves x (16 tokens x 128 sentences). LDS 24 KB -> 4+ blocks/CU.
// ---------------------------------------------------------------------------
__global__ __launch_bounds__(256, 4) void mi_main_kernel(
    const float* __restrict__ tok0, const float* __restrict__ tok1,
    const int* __restrict__ len0, const int* __restrict__ len1,
    const short* __restrict__ packed, float* __restrict__ acc_ws)
{
    const int side = blockIdx.y;
    const float* tok = side ? tok1 : tok0;
    const int*   len = side ? len1 : len0;

    const int tile   = blockIdx.x;       // 0..511
    const int b_sent = tile >> 2;        // 4 tiles per sentence
    const int toff   = (tile & 3) * TM;
    const int count  = max(1, len[b_sent]) - toff;
    if (count <= 0) return;              // uniform whole-block exit
    const int tb     = b_sent * L_TOK + toff;

    const int tid  = threadIdx.x;
    const int wave = tid >> 6;           // 0..3
    const int lane = tid & 63;
    const int lrow = lane & 15;
    const int kgrp = lane >> 4;

    __shared__ short Bs[3][4096];        // 3 x 8 KB shared B buffers
    __shared__ float sred[8];

    // A source: lane's own fragment rows (clamped; dups hit cache, masked
    // rows skipped in epilogue). 8 consecutive floats = 2 float4.
    const int arow = min(wave * 16 + lrow, count - 1);
    const float* asrc = tok + (size_t)(tb + arow) * D_DIM + kgrp * 8;
    const short* bchunk = packed + (size_t)side * NKB * 4096;
    const int boff0 = ((wave * 2 + 0) * 64 + lane) * 8;
    const int boff1 = ((wave * 2 + 1) * 64 + lane) * 8;

    f32x4 acc[8];
#pragma unroll
    for (int n = 0; n < 8; ++n) acc[n] = (f32x4){0.f, 0.f, 0.f, 0.f};

    f32x4 A0_0, A0_1, A1_0, A1_1;        // two A register sets (ping-pong)

    auto stageB = [&](int buf, int kb) {         // exactly 2 gl_lds per wave
        const short* bc = bchunk + (size_t)kb * 4096;
        gl_lds16(bc + boff0, &Bs[buf][(wave * 2 + 0) * 512]);
        gl_lds16(bc + boff1, &Bs[buf][(wave * 2 + 1) * 512]);
    };

#define LOADA(D0, D1, KB) do {                                               \
        const volatile f32x4* _vp =                                          \
            reinterpret_cast<const volatile f32x4*>(asrc + (KB) * BK);       \
        D0 = _vp[0]; D1 = _vp[1];                                            \
    } while (0)

    auto compute = [&](int buf, const f32x4& a0, const f32x4& a1) {
        const bf16x8 af = cvt8f(a0, a1);         // compiler waits A here
#pragma unroll
        for (int n = 0; n < 8; ++n) {
            bf16x8 b = *reinterpret_cast<const bf16x8*>(&Bs[buf][(n * 64 + lane) * 8]);
            acc[n] = __builtin_amdgcn_mfma_f32_16x16x32_bf16(af, b, acc[n], 0, 0, 0);
        }
    };

#define WAITB(N) do {                                                        \
        asm volatile("s_waitcnt vmcnt(" #N ")" ::: "memory");                \
        __builtin_amdgcn_s_barrier();                                        \
        __builtin_amdgcn_sched_barrier(0);                                   \
    } while (0)

    // steady step kb: stage B(kb+2) -> compute(kb) -> load A(kb+2) into the
    // set just consumed -> drain B(kb+1) (keep A(kb+1),B(kb+2),A(kb+2)=6).
#define STEP(KB, BUFC, BUFS, AC0, AC1)  do {                                 \
        stageB(BUFS, (KB) + 2);                                              \
        compute(BUFC, AC0, AC1);                                             \
        LOADA(AC0, AC1, (KB) + 2);                                           \
        WAITB(6);                                                            \
    } while (0)

    // prologue: B0,B1 staged; A0,A1 loaded; drain B0 (keep B1,A0,A1 = 6)
    stageB(0, 0);
    stageB(1, 1);
    LOADA(A0_0, A0_1, 0);
    LOADA(A1_0, A1_1, 1);
    WAITB(6);

#pragma unroll 1
    for (int t = 0; t < 5; ++t) {        // kb = 6t .. 6t+5, 0..29
        STEP(6 * t + 0, 0, 2, A0_0, A0_1);
        STEP(6 * t + 1, 1, 0, A1_0, A1_1);
        STEP(6 * t + 2, 2, 1, A0_0, A0_1);
        STEP(6 * t + 3, 0, 2, A1_0, A1_1);
        STEP(6 * t + 4, 1, 0, A0_0, A0_1);
        STEP(6 * t + 5, 2, 1, A1_0, A1_1);
    }
    // tail: kb=30 (buf 0, set 0), drain B31 (keep A31=2); kb=31 (buf 1, set 1)
    compute(0, A0_0, A0_1);
    asm volatile("s_waitcnt vmcnt(2)" ::: "memory");
    __builtin_amdgcn_s_barrier();
    __builtin_amdgcn_sched_barrier(0);
    compute(1, A1_0, A1_1);

#undef STEP
#undef WAITB
#undef LOADA

    // ---- epilogue: masked softplus reduction ----
    // C/D layout: col = lane&15 (sentence), row = kgrp*4 + j (token in frag)
    float ep = 0.f, en = 0.f;
#pragma unroll
    for (int n = 0; n < 8; ++n) {
        const int g = n * 16 + lrow;               // global sentence id
#pragma unroll
        for (int j = 0; j < 4; ++j) {
            const int rl = wave * 16 + kgrp * 4 + j;   // local token row
            if (rl < count) {
                float res = acc[n][j];
                float sp  = softplus_f(res);
                if (g == b_sent) ep += res - sp;   // -softplus(-res)
                else             en += sp;         // softplus(-res)+res
            }
        }
    }

#pragma unroll
    for (int off = 32; off; off >>= 1) {
        ep += __shfl_down(ep, off);
        en += __shfl_down(en, off);
    }
    if (lane == 0) { sred[wave * 2] = ep; sred[wave * 2 + 1] = en; }
    __syncthreads();
    if (tid == 0) {
        float tep = sred[0] + sred[2] + sred[4] + sred[6];
        float ten = sred[1] + sred[3] + sred[5] + sred[7];
        atomicAdd(&acc_ws[side * 2 + 0], tep);
        atomicAdd(&acc_ws[side * 2 + 1], ten);
    }
}

__global__ void mi_finalize_kernel(const int* __restrict__ len0,
                                   const int* __restrict__ len1,
                                   const float* __restrict__ acc_ws,
                                   float* __restrict__ out)
{
    const int lane = threadIdx.x;   // 1 wave
    int s0 = 0, s1 = 0;
    for (int i = lane; i < B_SENT; i += 64) {
        s0 += max(1, len0[i]);
        s1 += max(1, len1[i]);
    }
#pragma unroll
    for (int off = 32; off; off >>= 1) {
        s0 += __shfl_down(s0, off);
        s1 += __shfl_down(s1, off);
    }
    if (lane == 0) {
        const float num_nodes = (float)(s0 + s1);
        const float ep = acc_ws[0] + acc_ws[2];
        const float en = acc_ws[1] + acc_ws[3];
        out[0] = en / (num_nodes * (float)(B_SENT - 1)) - ep / num_nodes;
        out[1] = ((float)s0 + (float)s1) / (2.0f * (float)B_SENT);
    }
}

extern "C" void kernel_launch(void* const* d_in, const int* in_sizes, int n_in,
                              void* d_out, int out_size, void* d_ws, size_t ws_size,
                              hipStream_t stream) {
    const float* tok0  = (const float*)d_in[0];
    const float* tok1  = (const float*)d_in[1];
    const float* glob0 = (const float*)d_in[2];
    const float* glob1 = (const float*)d_in[3];
    const int*   len0  = (const int*)d_in[4];
    const int*   len1  = (const int*)d_in[5];
    float* out = (float*)d_out;

    float* acc    = (float*)d_ws;                       // 4 floats @ offset 0
    short* packed = (short*)((char*)d_ws + 256);        // 512 KB bf16 fragments

    hipMemsetAsync(d_ws, 0, 256, stream);
    pack_g_kernel<<<128, 256, 0, stream>>>(glob0, glob1, packed);

    dim3 grid(32768 / TM, 2);   // 512 token-tiles x 2 sides
    mi_main_kernel<<<grid, 256, 0, stream>>>(tok0, tok1, len0, len1, packed, acc);
    mi_finalize_kernel<<<1, 64, 0, stream>>>(len0, len1, acc, out);
}